// Round 2
// baseline (1193.425 us; speedup 1.0000x reference)
//
#include <hip/hip_runtime.h>

#define N_NODES 100000
#define N_EDGES 1250000
#define FEATS 64

// ---------------------------------------------------------------------------
// Kernel 1: scatter-add  ah[dst[e]][:] += h[src[e]][:]   (all fp32)
// 16 threads per edge; each thread handles 4 contiguous floats (float4 load),
// 4 fp32 hw atomics. Total 80M global_atomic_add_f32.
// ---------------------------------------------------------------------------
__global__ __launch_bounds__(256) void scatter_kernel(
        const float* __restrict__ h,
        const int* __restrict__ src,
        const int* __restrict__ dst,
        float* __restrict__ ah) {
    long long w = (long long)blockIdx.x * blockDim.x + threadIdx.x;
    if (w >= (long long)N_EDGES * 16) return;
    int e = (int)(w >> 4);
    int c = (int)(w & 15);

    int s = src[e];
    int d = dst[e];

    const float4* hp = (const float4*)(h + (size_t)s * FEATS + c * 4);
    float4 v = *hp;

    float* ap = ah + (size_t)d * FEATS + c * 4;
    unsafeAtomicAdd(ap + 0, v.x);
    unsafeAtomicAdd(ap + 1, v.y);
    unsafeAtomicAdd(ap + 2, v.z);
    unsafeAtomicAdd(ap + 3, v.w);
}

// ---------------------------------------------------------------------------
// Kernel 2: out[n][o] = relu( b[o] + sum_k ah[n][k] * W[o][k] )  (all fp32)
// W^T staged in LDS so lanes (o consecutive) hit consecutive banks.
// 4 nodes per block-iteration (256 threads = 4 x 64 outputs).
// ---------------------------------------------------------------------------
__global__ __launch_bounds__(256) void linear_relu_kernel(
        const float* __restrict__ ah,
        const float* __restrict__ W,   // [64][64] row-major [o][k]
        const float* __restrict__ b,   // [64]
        float* __restrict__ out) {
    __shared__ float sWt[FEATS * FEATS];  // [k][o]
    __shared__ float sb[FEATS];
    __shared__ float srow[4 * FEATS];

    int tid = threadIdx.x;
    for (int i = tid; i < FEATS * FEATS; i += 256) {
        int o = i >> 6, k = i & 63;
        sWt[k * FEATS + o] = W[i];
    }
    if (tid < FEATS) sb[tid] = b[tid];
    __syncthreads();

    int o  = tid & 63;
    int ln = tid >> 6;   // 0..3 local node

    const int n_groups = (N_NODES + 3) / 4;
    for (int g = blockIdx.x; g < n_groups; g += gridDim.x) {
        int n0 = g * 4;
        // stage 4 ah rows (256 floats), fully coalesced
        long long idx = (long long)n0 * FEATS + tid;
        float v = (idx < (long long)N_NODES * FEATS) ? ah[idx] : 0.0f;
        __syncthreads();           // protect srow reads from previous iteration
        srow[tid] = v;
        __syncthreads();

        int n = n0 + ln;
        float acc = sb[o];
#pragma unroll
        for (int k = 0; k < FEATS; ++k) {
            acc = fmaf(srow[ln * FEATS + k], sWt[k * FEATS + o], acc);
        }
        acc = fmaxf(acc, 0.0f);
        if (n < N_NODES) out[(size_t)n * FEATS + o] = acc;
    }
}

extern "C" void kernel_launch(void* const* d_in, const int* in_sizes, int n_in,
                              void* d_out, int out_size, void* d_ws, size_t ws_size,
                              hipStream_t stream) {
    const float* h   = (const float*)d_in[0];  // fp32 [100000,64]
    const int*   src = (const int*)d_in[1];    // int32 [1250000]
    const int*   dst = (const int*)d_in[2];    // int32 [1250000]
    const float* W   = (const float*)d_in[3];  // fp32 [64,64]
    const float* b   = (const float*)d_in[4];  // fp32 [64]
    float* out = (float*)d_out;                // fp32 [100000,64]

    float* ah = (float*)d_ws;  // fp32 accumulator [100000,64] = 25.6 MB

    // zero the accumulator (d_ws is re-poisoned to 0xAA before every launch)
    hipMemsetAsync(ah, 0, (size_t)N_NODES * FEATS * sizeof(float), stream);

    {
        long long work = (long long)N_EDGES * 16;
        int blocks = (int)((work + 255) / 256);
        scatter_kernel<<<blocks, 256, 0, stream>>>(h, src, dst, ah);
    }
    {
        linear_relu_kernel<<<1024, 256, 0, stream>>>(ah, W, b, out);
    }
}

// Round 3
// 591.204 us; speedup vs baseline: 2.0186x; 2.0186x over previous
//
#include <hip/hip_runtime.h>

#define N_NODES 100000
#define N_EDGES 1250000
#define FEATS 64

// ---------------------------------------------------------------------------
// Workspace layout (ints):
//   cnt     [N_NODES]      histogram of dst
//   offs    [N_NODES+1]    exclusive prefix sum (CSR row offsets)
//   cursor  [N_NODES]      running fill cursor (starts at offs)
//   csr_src [N_EDGES]      src node ids grouped by dst
// total ~6.2 MB (well under the 25.6 MB proven available in d_ws)
// ---------------------------------------------------------------------------

__global__ __launch_bounds__(256) void count_kernel(
        const int* __restrict__ dst, int* __restrict__ cnt) {
    int e = blockIdx.x * blockDim.x + threadIdx.x;
    if (e < N_EDGES) atomicAdd(&cnt[dst[e]], 1);
}

// Single-block exclusive scan of cnt[0..N) -> offs[0..N], cursor copy.
__global__ __launch_bounds__(1024) void scan_kernel(
        const int* __restrict__ cnt,
        int* __restrict__ offs,
        int* __restrict__ cursor) {
    __shared__ int lsum[1024];
    const int tid = threadIdx.x;
    const int CH = (N_NODES + 1023) / 1024;   // 98 elements per thread
    const int begin = tid * CH;
    const int end   = min(begin + CH, N_NODES);

    int s = 0;
    for (int i = begin; i < end; ++i) s += cnt[i];
    lsum[tid] = s;
    __syncthreads();

    // inclusive Hillis-Steele scan over 1024 partial sums
    for (int off = 1; off < 1024; off <<= 1) {
        int y = (tid >= off) ? lsum[tid - off] : 0;
        __syncthreads();
        lsum[tid] += y;
        __syncthreads();
    }

    int run = (tid > 0) ? lsum[tid - 1] : 0;  // exclusive prefix of my chunk
    for (int i = begin; i < end; ++i) {
        offs[i]   = run;
        cursor[i] = run;
        run += cnt[i];
    }
    if (tid == 0) offs[N_NODES] = lsum[1023];  // == N_EDGES
}

__global__ __launch_bounds__(256) void fill_kernel(
        const int* __restrict__ src,
        const int* __restrict__ dst,
        int* __restrict__ cursor,
        int* __restrict__ csr_src) {
    int e = blockIdx.x * blockDim.x + threadIdx.x;
    if (e < N_EDGES) {
        int pos = atomicAdd(&cursor[dst[e]], 1);
        csr_src[pos] = src[e];
    }
}

// ---------------------------------------------------------------------------
// Fused gather + linear + bias + relu.
// One wave (64 lanes) per node, lane = feature index.
//   acc[lane] = sum over in-edges of h[src][lane]   (256B coalesced per edge)
//   out[n][o=lane] = relu(b[o] + sum_k acc_row[k] * W[o][k])  via LDS
// ---------------------------------------------------------------------------
__global__ __launch_bounds__(256) void gather_linear_kernel(
        const float* __restrict__ h,
        const int* __restrict__ offs,
        const int* __restrict__ csr_src,
        const float* __restrict__ W,    // [o][k] row-major
        const float* __restrict__ b,
        float* __restrict__ out) {
    __shared__ float sWt[FEATS * FEATS];   // [k][o]
    __shared__ float sb[FEATS];
    __shared__ float srow[4][FEATS];       // one row per wave

    const int tid  = threadIdx.x;
    const int lane = tid & 63;
    const int wv   = tid >> 6;             // 0..3

    for (int i = tid; i < FEATS * FEATS; i += 256) {
        int o = i >> 6, k = i & 63;
        sWt[k * FEATS + o] = W[i];
    }
    if (tid < FEATS) sb[tid] = b[tid];
    __syncthreads();

    const int n_waves_total = gridDim.x * 4;
    for (int n = blockIdx.x * 4 + wv; n < N_NODES; n += n_waves_total) {
        int beg = offs[n];
        int end = offs[n + 1];

        float acc = 0.0f;
        for (int base = beg; base < end; base += 64) {
            int m = end - base;
            if (m > 64) m = 64;
            int idx = (lane < m) ? csr_src[base + lane] : 0;
            for (int t = 0; t < m; ++t) {
                int s = __shfl(idx, t, 64);
                acc += h[(size_t)s * FEATS + lane];
            }
        }

        // 64x64 linear via LDS round-trip (wave-private region, in-wave dep
        // handled by lgkmcnt the compiler inserts)
        srow[wv][lane] = acc;
        float o_acc = sb[lane];
#pragma unroll
        for (int k = 0; k < FEATS; ++k) {
            o_acc = fmaf(srow[wv][k], sWt[k * FEATS + lane], o_acc);
        }
        out[(size_t)n * FEATS + lane] = fmaxf(o_acc, 0.0f);
    }
}

extern "C" void kernel_launch(void* const* d_in, const int* in_sizes, int n_in,
                              void* d_out, int out_size, void* d_ws, size_t ws_size,
                              hipStream_t stream) {
    const float* h   = (const float*)d_in[0];  // fp32 [100000,64]
    const int*   src = (const int*)d_in[1];    // int32 [1250000]
    const int*   dst = (const int*)d_in[2];    // int32 [1250000]
    const float* W   = (const float*)d_in[3];  // fp32 [64,64]
    const float* b   = (const float*)d_in[4];  // fp32 [64]
    float* out = (float*)d_out;                // fp32 [100000,64]

    int* cnt     = (int*)d_ws;
    int* offs    = cnt + N_NODES;
    int* cursor  = offs + N_NODES + 1;
    int* csr_src = cursor + N_NODES;

    hipMemsetAsync(cnt, 0, N_NODES * sizeof(int), stream);

    {
        int blocks = (N_EDGES + 255) / 256;
        count_kernel<<<blocks, 256, 0, stream>>>(dst, cnt);
    }
    scan_kernel<<<1, 1024, 0, stream>>>(cnt, offs, cursor);
    {
        int blocks = (N_EDGES + 255) / 256;
        fill_kernel<<<blocks, 256, 0, stream>>>(src, dst, cursor, csr_src);
    }
    gather_linear_kernel<<<2048, 256, 0, stream>>>(h, offs, csr_src, W, b, out);
}

// Round 4
// 371.321 us; speedup vs baseline: 3.2140x; 1.5922x over previous
//
#include <hip/hip_runtime.h>

#define N_NODES 100000
#define N_EDGES 1250000
#define FEATS 64

#define SCAN_CHUNK 1024
#define SCAN_NB ((N_NODES + SCAN_CHUNK - 1) / SCAN_CHUNK)   // 98

// ---------------------------------------------------------------------------
// Workspace layout (ints, all int4-aligned):
//   cnt     [100000]   histogram of dst
//   cursor  [100000]   running fill cursor
//   temp    [100000]   per-block exclusive local scan
//   bsum    [128]      per-block totals
//   bscan   [128]      exclusive scan of bsum
//   csr_src [1250000]  src ids grouped by dst
//   offs    [100001]   CSR row offsets
// total ~6.6 MB
// ---------------------------------------------------------------------------

__global__ __launch_bounds__(256) void count_kernel(
        const int* __restrict__ dst, int* __restrict__ cnt) {
    int e = blockIdx.x * blockDim.x + threadIdx.x;
    if (e < N_EDGES) atomicAdd(&cnt[dst[e]], 1);
}

// Pass 1: per-block (1024 elems) exclusive local scan -> temp, total -> bsum
__global__ __launch_bounds__(256) void scan_pass1(
        const int* __restrict__ cnt,
        int* __restrict__ temp,
        int* __restrict__ bsum) {
    __shared__ int lsum[256];
    const int t = threadIdx.x;
    const int base = blockIdx.x * SCAN_CHUNK + t * 4;

    int v0 = 0, v1 = 0, v2 = 0, v3 = 0;
    if (base + 3 < N_NODES) {
        const int4 v = *(const int4*)(cnt + base);
        v0 = v.x; v1 = v.y; v2 = v.z; v3 = v.w;
    } else {
        if (base + 0 < N_NODES) v0 = cnt[base + 0];
        if (base + 1 < N_NODES) v1 = cnt[base + 1];
        if (base + 2 < N_NODES) v2 = cnt[base + 2];
        if (base + 3 < N_NODES) v3 = cnt[base + 3];
    }
    lsum[t] = v0 + v1 + v2 + v3;
    __syncthreads();
    for (int off = 1; off < 256; off <<= 1) {
        int y = (t >= off) ? lsum[t - off] : 0;
        __syncthreads();
        lsum[t] += y;
        __syncthreads();
    }
    int toff = (t > 0) ? lsum[t - 1] : 0;   // exclusive thread offset

    int e0 = toff;
    int e1 = toff + v0;
    int e2 = e1 + v1;
    int e3 = e2 + v2;
    if (base + 3 < N_NODES) {
        *(int4*)(temp + base) = make_int4(e0, e1, e2, e3);
    } else {
        if (base + 0 < N_NODES) temp[base + 0] = e0;
        if (base + 1 < N_NODES) temp[base + 1] = e1;
        if (base + 2 < N_NODES) temp[base + 2] = e2;
        if (base + 3 < N_NODES) temp[base + 3] = e3;
    }
    if (t == 255) bsum[blockIdx.x] = lsum[255];
}

// Pass 2: single small block scans 98 block totals (exclusive) -> bscan
__global__ __launch_bounds__(128) void scan_pass2(
        const int* __restrict__ bsum, int* __restrict__ bscan) {
    __shared__ int s[128];
    const int t = threadIdx.x;
    s[t] = (t < SCAN_NB) ? bsum[t] : 0;
    __syncthreads();
    for (int off = 1; off < 128; off <<= 1) {
        int y = (t >= off) ? s[t - off] : 0;
        __syncthreads();
        s[t] += y;
        __syncthreads();
    }
    if (t < SCAN_NB) bscan[t] = (t > 0) ? s[t - 1] : 0;
}

// Pass 3: offs[i] = cursor[i] = temp[i] + bscan[block]; offs[N] = N_EDGES
__global__ __launch_bounds__(256) void scan_pass3(
        const int* __restrict__ temp,
        const int* __restrict__ bscan,
        int* __restrict__ offs,
        int* __restrict__ cursor) {
    const int t = threadIdx.x;
    const int base = blockIdx.x * SCAN_CHUNK + t * 4;
    const int boff = bscan[blockIdx.x];

    if (base + 3 < N_NODES) {
        int4 v = *(const int4*)(temp + base);
        v.x += boff; v.y += boff; v.z += boff; v.w += boff;
        *(int4*)(offs + base)   = v;
        *(int4*)(cursor + base) = v;
    } else {
        for (int j = 0; j < 4; ++j) {
            if (base + j < N_NODES) {
                int v = temp[base + j] + boff;
                offs[base + j]   = v;
                cursor[base + j] = v;
            }
        }
    }
    if (blockIdx.x == 0 && t == 0) offs[N_NODES] = N_EDGES;  // dst always in range
}

__global__ __launch_bounds__(256) void fill_kernel(
        const int* __restrict__ src,
        const int* __restrict__ dst,
        int* __restrict__ cursor,
        int* __restrict__ csr_src) {
    int e = blockIdx.x * blockDim.x + threadIdx.x;
    if (e < N_EDGES) {
        int pos = atomicAdd(&cursor[dst[e]], 1);
        csr_src[pos] = src[e];
    }
}

// ---------------------------------------------------------------------------
// Fused gather + linear + bias + relu. One wave per node, lane = feature.
// ---------------------------------------------------------------------------
__global__ __launch_bounds__(256) void gather_linear_kernel(
        const float* __restrict__ h,
        const int* __restrict__ offs,
        const int* __restrict__ csr_src,
        const float* __restrict__ W,    // [o][k] row-major
        const float* __restrict__ b,
        float* __restrict__ out) {
    __shared__ float sWt[FEATS * FEATS];   // [k][o]
    __shared__ float sb[FEATS];
    __shared__ float srow[4][FEATS];

    const int tid  = threadIdx.x;
    const int lane = tid & 63;
    const int wv   = tid >> 6;

    for (int i = tid; i < FEATS * FEATS; i += 256) {
        int o = i >> 6, k = i & 63;
        sWt[k * FEATS + o] = W[i];
    }
    if (tid < FEATS) sb[tid] = b[tid];
    __syncthreads();

    const int n_waves_total = gridDim.x * 4;
    for (int n = blockIdx.x * 4 + wv; n < N_NODES; n += n_waves_total) {
        int beg = offs[n];
        int end = offs[n + 1];

        float acc = 0.0f;
        for (int base = beg; base < end; base += 64) {
            int m = end - base;
            if (m > 64) m = 64;
            int idx = (lane < m) ? csr_src[base + lane] : 0;
            for (int t = 0; t < m; ++t) {
                int s = __shfl(idx, t, 64);
                acc += h[(size_t)s * FEATS + lane];
            }
        }

        srow[wv][lane] = acc;
        float o_acc = sb[lane];
#pragma unroll
        for (int k = 0; k < FEATS; ++k) {
            o_acc = fmaf(srow[wv][k], sWt[k * FEATS + lane], o_acc);
        }
        out[(size_t)n * FEATS + lane] = fmaxf(o_acc, 0.0f);
    }
}

extern "C" void kernel_launch(void* const* d_in, const int* in_sizes, int n_in,
                              void* d_out, int out_size, void* d_ws, size_t ws_size,
                              hipStream_t stream) {
    const float* h   = (const float*)d_in[0];
    const int*   src = (const int*)d_in[1];
    const int*   dst = (const int*)d_in[2];
    const float* W   = (const float*)d_in[3];
    const float* b   = (const float*)d_in[4];
    float* out = (float*)d_out;

    int* ws      = (int*)d_ws;
    int* cnt     = ws;                       // 100000
    int* cursor  = cnt + N_NODES;            // 100000
    int* temp    = cursor + N_NODES;         // 100000
    int* bsum    = temp + N_NODES;           // 128
    int* bscan   = bsum + 128;               // 128
    int* csr_src = bscan + 128;              // 1250000
    int* offs    = csr_src + N_EDGES;        // 100001

    hipMemsetAsync(cnt, 0, N_NODES * sizeof(int), stream);

    count_kernel<<<(N_EDGES + 255) / 256, 256, 0, stream>>>(dst, cnt);
    scan_pass1<<<SCAN_NB, 256, 0, stream>>>(cnt, temp, bsum);
    scan_pass2<<<1, 128, 0, stream>>>(bsum, bscan);
    scan_pass3<<<SCAN_NB, 256, 0, stream>>>(temp, bscan, offs, cursor);
    fill_kernel<<<(N_EDGES + 255) / 256, 256, 0, stream>>>(src, dst, cursor, csr_src);
    gather_linear_kernel<<<2048, 256, 0, stream>>>(h, offs, csr_src, W, b, out);
}

// Round 5
// 298.514 us; speedup vs baseline: 3.9979x; 1.2439x over previous
//
#include <hip/hip_runtime.h>

#define N_NODES 100000
#define N_EDGES 1250000
#define FEATS 64

#define SCAN_CHUNK 1024
#define SCAN_NB ((N_NODES + SCAN_CHUNK - 1) / SCAN_CHUNK)   // 98

// ---------------------------------------------------------------------------
// Workspace layout (ints, all int4-aligned):
//   cnt     [100000]   histogram of dst
//   cursor  [100000]   running fill cursor
//   temp    [100000]   per-block exclusive local scan
//   bsum    [128]      per-block totals
//   bscan   [128]      exclusive scan of bsum
//   csr_src [1250000]  src ids grouped by dst
//   offs    [100001]   CSR row offsets
// ---------------------------------------------------------------------------

__global__ __launch_bounds__(256) void count_kernel(
        const int* __restrict__ dst, int* __restrict__ cnt) {
    int e = blockIdx.x * blockDim.x + threadIdx.x;
    if (e < N_EDGES) atomicAdd(&cnt[dst[e]], 1);
}

__global__ __launch_bounds__(256) void scan_pass1(
        const int* __restrict__ cnt,
        int* __restrict__ temp,
        int* __restrict__ bsum) {
    __shared__ int lsum[256];
    const int t = threadIdx.x;
    const int base = blockIdx.x * SCAN_CHUNK + t * 4;

    int v0 = 0, v1 = 0, v2 = 0, v3 = 0;
    if (base + 3 < N_NODES) {
        const int4 v = *(const int4*)(cnt + base);
        v0 = v.x; v1 = v.y; v2 = v.z; v3 = v.w;
    } else {
        if (base + 0 < N_NODES) v0 = cnt[base + 0];
        if (base + 1 < N_NODES) v1 = cnt[base + 1];
        if (base + 2 < N_NODES) v2 = cnt[base + 2];
    }
    lsum[t] = v0 + v1 + v2 + v3;
    __syncthreads();
    for (int off = 1; off < 256; off <<= 1) {
        int y = (t >= off) ? lsum[t - off] : 0;
        __syncthreads();
        lsum[t] += y;
        __syncthreads();
    }
    int toff = (t > 0) ? lsum[t - 1] : 0;

    int e0 = toff;
    int e1 = toff + v0;
    int e2 = e1 + v1;
    int e3 = e2 + v2;
    if (base + 3 < N_NODES) {
        *(int4*)(temp + base) = make_int4(e0, e1, e2, e3);
    } else {
        if (base + 0 < N_NODES) temp[base + 0] = e0;
        if (base + 1 < N_NODES) temp[base + 1] = e1;
        if (base + 2 < N_NODES) temp[base + 2] = e2;
    }
    if (t == 255) bsum[blockIdx.x] = lsum[255];
}

__global__ __launch_bounds__(128) void scan_pass2(
        const int* __restrict__ bsum, int* __restrict__ bscan) {
    __shared__ int s[128];
    const int t = threadIdx.x;
    s[t] = (t < SCAN_NB) ? bsum[t] : 0;
    __syncthreads();
    for (int off = 1; off < 128; off <<= 1) {
        int y = (t >= off) ? s[t - off] : 0;
        __syncthreads();
        s[t] += y;
        __syncthreads();
    }
    if (t < SCAN_NB) bscan[t] = (t > 0) ? s[t - 1] : 0;
}

__global__ __launch_bounds__(256) void scan_pass3(
        const int* __restrict__ temp,
        const int* __restrict__ bscan,
        int* __restrict__ offs,
        int* __restrict__ cursor) {
    const int t = threadIdx.x;
    const int base = blockIdx.x * SCAN_CHUNK + t * 4;
    const int boff = bscan[blockIdx.x];

    if (base + 3 < N_NODES) {
        int4 v = *(const int4*)(temp + base);
        v.x += boff; v.y += boff; v.z += boff; v.w += boff;
        *(int4*)(offs + base)   = v;
        *(int4*)(cursor + base) = v;
    } else {
        for (int j = 0; j < 4; ++j) {
            if (base + j < N_NODES) {
                int v = temp[base + j] + boff;
                offs[base + j]   = v;
                cursor[base + j] = v;
            }
        }
    }
    if (blockIdx.x == 0 && t == 0) offs[N_NODES] = N_EDGES;
}

__global__ __launch_bounds__(256) void fill_kernel(
        const int* __restrict__ src,
        const int* __restrict__ dst,
        int* __restrict__ cursor,
        int* __restrict__ csr_src) {
    int e = blockIdx.x * blockDim.x + threadIdx.x;
    if (e < N_EDGES) {
        int pos = atomicAdd(&cursor[dst[e]], 1);
        csr_src[pos] = src[e];
    }
}

// ---------------------------------------------------------------------------
// Fused gather + linear + bias + relu. One wave per node.
// Gather: 16 lanes per h-row (float4/lane) -> 4 edges per wave-instruction.
// Linear: W row held in 64 VGPRs per lane (o = lane), row broadcast via
//         b128 LDS reads. No sWt LDS array, no per-edge shfl.
// All LDS regions are wave-private -> no __syncthreads needed.
// ---------------------------------------------------------------------------
__global__ __launch_bounds__(256) void gather_linear_kernel(
        const float* __restrict__ h,
        const int* __restrict__ offs,
        const int* __restrict__ csr_src,
        const float* __restrict__ W,    // [o][k] row-major
        const float* __restrict__ b,
        float* __restrict__ out) {
    __shared__ int   sidx[4][64];
    __shared__ float srow[4][FEATS];

    const int tid  = threadIdx.x;
    const int lane = tid & 63;
    const int wv   = tid >> 6;
    const int sub  = lane >> 4;          // 0..3: which edge of the quad
    const int fo   = (lane & 15) * 4;    // feature offset of my float4

    // W row for output o = lane into registers (16 KB total per wave, L2-hot)
    float wr[FEATS];
#pragma unroll
    for (int kk = 0; kk < 16; ++kk) {
        float4 w4 = *(const float4*)(W + (size_t)lane * FEATS + kk * 4);
        wr[kk * 4 + 0] = w4.x;
        wr[kk * 4 + 1] = w4.y;
        wr[kk * 4 + 2] = w4.z;
        wr[kk * 4 + 3] = w4.w;
    }
    const float bias = b[lane];

    const int n_waves_total = gridDim.x * 4;
    for (int n = blockIdx.x * 4 + wv; n < N_NODES; n += n_waves_total) {
        const int beg = offs[n];
        const int end = offs[n + 1];

        float4 acc = make_float4(0.f, 0.f, 0.f, 0.f);
        for (int base = beg; base < end; base += 64) {
            int m = end - base;
            if (m > 64) m = 64;
            if (lane < m) sidx[wv][lane] = csr_src[base + lane];
            // wave-private LDS: compiler inserts lgkmcnt wait, no barrier
            for (int t = 0; t < m; t += 4) {
                int e = t + sub;
                if (e < m) {
                    int s = sidx[wv][e];
                    float4 v = *(const float4*)(h + (size_t)s * FEATS + fo);
                    acc.x += v.x; acc.y += v.y; acc.z += v.z; acc.w += v.w;
                }
            }
        }

        // reduce partials across the 4 sub-groups (lanes lane^16, lane^32)
        acc.x += __shfl_xor(acc.x, 16, 64);
        acc.y += __shfl_xor(acc.y, 16, 64);
        acc.z += __shfl_xor(acc.z, 16, 64);
        acc.w += __shfl_xor(acc.w, 16, 64);
        acc.x += __shfl_xor(acc.x, 32, 64);
        acc.y += __shfl_xor(acc.y, 32, 64);
        acc.z += __shfl_xor(acc.z, 32, 64);
        acc.w += __shfl_xor(acc.w, 32, 64);

        if (lane < 16) *(float4*)&srow[wv][fo] = acc;   // 256B, conflict-free

        // out[n][o=lane] = relu(bias + sum_k srow[k] * wr[k])
        float o_acc = bias;
#pragma unroll
        for (int k4 = 0; k4 < 16; ++k4) {
            float4 r = *(const float4*)&srow[wv][k4 * 4];  // b128 broadcast
            o_acc = fmaf(r.x, wr[k4 * 4 + 0], o_acc);
            o_acc = fmaf(r.y, wr[k4 * 4 + 1], o_acc);
            o_acc = fmaf(r.z, wr[k4 * 4 + 2], o_acc);
            o_acc = fmaf(r.w, wr[k4 * 4 + 3], o_acc);
        }
        out[(size_t)n * FEATS + lane] = fmaxf(o_acc, 0.0f);
    }
}

extern "C" void kernel_launch(void* const* d_in, const int* in_sizes, int n_in,
                              void* d_out, int out_size, void* d_ws, size_t ws_size,
                              hipStream_t stream) {
    const float* h   = (const float*)d_in[0];
    const int*   src = (const int*)d_in[1];
    const int*   dst = (const int*)d_in[2];
    const float* W   = (const float*)d_in[3];
    const float* b   = (const float*)d_in[4];
    float* out = (float*)d_out;

    int* ws      = (int*)d_ws;
    int* cnt     = ws;
    int* cursor  = cnt + N_NODES;
    int* temp    = cursor + N_NODES;
    int* bsum    = temp + N_NODES;
    int* bscan   = bsum + 128;
    int* csr_src = bscan + 128;
    int* offs    = csr_src + N_EDGES;

    hipMemsetAsync(cnt, 0, N_NODES * sizeof(int), stream);

    count_kernel<<<(N_EDGES + 255) / 256, 256, 0, stream>>>(dst, cnt);
    scan_pass1<<<SCAN_NB, 256, 0, stream>>>(cnt, temp, bsum);
    scan_pass2<<<1, 128, 0, stream>>>(bsum, bscan);
    scan_pass3<<<SCAN_NB, 256, 0, stream>>>(temp, bscan, offs, cursor);
    fill_kernel<<<(N_EDGES + 255) / 256, 256, 0, stream>>>(src, dst, cursor, csr_src);
    gather_linear_kernel<<<2048, 256, 0, stream>>>(h, offs, csr_src, W, b, out);
}